// Round 1
// baseline (553.886 us; speedup 1.0000x reference)
//
#include <hip/hip_runtime.h>
#include <hip/hip_bf16.h>
#include <cstdint>

#define PI_F 3.14159265358979323846f

typedef __attribute__((ext_vector_type(8))) short bf16x8;
typedef __attribute__((ext_vector_type(4))) float f32x4;

__device__ __forceinline__ void gload_lds16(const void* g, void* l) {
  __builtin_amdgcn_global_load_lds(
      (const __attribute__((address_space(1))) void*)g,
      (__attribute__((address_space(3))) void*)l, 16, 0, 0);
}

// ---------------------------------------------------------------------------
// prep: feat = [cos(cond), sin(cond)] as bf16; z_new even cols = cond; zero ld
// ---------------------------------------------------------------------------
__global__ __launch_bounds__(256) void prep_feat_kernel(
    const float* __restrict__ z, __hip_bfloat16* __restrict__ feat,
    float* __restrict__ zout, float* __restrict__ logdet)
{
  int idx = blockIdx.x * 256 + threadIdx.x;    // B*512 threads
  int b = idx >> 9, j = idx & 511;
  float2 zz = ((const float2*)z)[idx];         // z[b][2j], z[b][2j+1]
  feat[(size_t)b * 1024 + j]       = __float2bfloat16(cosf(zz.x));
  feat[(size_t)b * 1024 + 512 + j] = __float2bfloat16(sinf(zz.x));
  zout[(size_t)b * 1024 + 2 * j]   = zz.x;
  if (idx < 8192) logdet[idx] = 0.f;
}

// ---------------------------------------------------------------------------
// transpose f32 [R][C] -> bf16 [C][R]
// ---------------------------------------------------------------------------
__global__ __launch_bounds__(256) void transpose_bf16_kernel(
    const float* __restrict__ src, __hip_bfloat16* __restrict__ dst, int R, int C)
{
  __shared__ float tile[32][33];
  int c0 = blockIdx.x * 32, r0 = blockIdx.y * 32;
  int x = threadIdx.x, y = threadIdx.y;        // 32 x 8
  #pragma unroll
  for (int i = 0; i < 32; i += 8)
    tile[y + i][x] = src[(size_t)(r0 + y + i) * C + c0 + x];
  __syncthreads();
  #pragma unroll
  for (int i = 0; i < 32; i += 8)
    dst[(size_t)(c0 + y + i) * R + r0 + x] = __float2bfloat16(tile[x][y + i]);
}

// ---------------------------------------------------------------------------
// GEMM1: h = relu(feat @ W1 + b1), M=8192 N=1024 K=1024, out bf16
// 128x128 tile, BK=64, 4 waves (each 32 rows x 128 cols), swizzled LDS
// ---------------------------------------------------------------------------
__global__ __launch_bounds__(256, 2) void gemm1_kernel(
    const __hip_bfloat16* __restrict__ A, const __hip_bfloat16* __restrict__ Bt,
    const float* __restrict__ bias, __hip_bfloat16* __restrict__ H)
{
  __shared__ __align__(16) char smem[32768];
  const int tid = threadIdx.x;
  const int lane = tid & 63;
  const int w = tid >> 6;
  const int m0 = blockIdx.x * 128;
  const int n0 = blockIdx.y * 128;
  const int lrow = lane >> 3;
  const int scol = ((lane & 7) ^ lrow) << 4;                 // swizzled src col
  const int fofs0 = ((lane >> 4) << 4) ^ ((lane & 7) << 4);  // frag read offset
  const int arow = w * 32 + (lane & 15);
  const int brow = (lane & 15);

  f32x4 acc[2][8];
  #pragma unroll
  for (int i = 0; i < 2; ++i)
    #pragma unroll
    for (int j = 0; j < 8; ++j) acc[i][j] = (f32x4){0.f, 0.f, 0.f, 0.f};

  const char* Abase = (const char*)A + (size_t)(m0 + lrow) * 2048 + scol;
  const char* Bbase = (const char*)Bt + (size_t)(n0 + lrow) * 2048 + scol;

  for (int kt = 0; kt < 16; ++kt) {
    const int k0b = kt * 128;  // bytes into the K dim
    __syncthreads();
    #pragma unroll
    for (int i = 0; i < 8; ++i) {
      int c = w + i * 4;                       // 0..31
      if (c < 16) gload_lds16(Abase + (size_t)c * 16384 + k0b, smem + c * 1024);
      else        gload_lds16(Bbase + (size_t)(c - 16) * 16384 + k0b,
                              smem + 16384 + (c - 16) * 1024);
    }
    asm volatile("s_waitcnt vmcnt(0)" ::: "memory");
    __syncthreads();
    #pragma unroll
    for (int ks = 0; ks < 2; ++ks) {
      const int fo = fofs0 ^ (ks << 6);
      bf16x8 a0 = *(const bf16x8*)(smem + arow * 128 + fo);
      bf16x8 a1 = *(const bf16x8*)(smem + (arow + 16) * 128 + fo);
      #pragma unroll
      for (int fn = 0; fn < 8; ++fn) {
        bf16x8 bb = *(const bf16x8*)(smem + 16384 + (brow + fn * 16) * 128 + fo);
        acc[0][fn] = __builtin_amdgcn_mfma_f32_16x16x32_bf16(a0, bb, acc[0][fn], 0, 0, 0);
        acc[1][fn] = __builtin_amdgcn_mfma_f32_16x16x32_bf16(a1, bb, acc[1][fn], 0, 0, 0);
      }
    }
  }
  #pragma unroll
  for (int fn = 0; fn < 8; ++fn) {
    int ncol = n0 + fn * 16 + (lane & 15);
    float bv = bias[ncol];
    #pragma unroll
    for (int mf = 0; mf < 2; ++mf) {
      int mrow = m0 + w * 32 + mf * 16 + ((lane >> 4) << 2);
      #pragma unroll
      for (int j = 0; j < 4; ++j) {
        float v = fmaxf(acc[mf][fn][j] + bv, 0.f);
        H[(size_t)(mrow + j) * 1024 + ncol] = __float2bfloat16(v);
      }
    }
  }
}

// ---------------------------------------------------------------------------
// GEMM2 + NCP epilogue: out = h @ W2 + b2 -> alpha/beta/rho -> z_new odd, ld
// M=8192, N=15360, K=1024. Tile 128x240 (8 t-groups of 30), BK=64, 4 waves.
// Epilogue: 4 chunks of 32 rows staged through LDS [32][241] f32.
// ---------------------------------------------------------------------------
__global__ __launch_bounds__(256, 2) void gemm2_ncp_kernel(
    const __hip_bfloat16* __restrict__ Hin, const __hip_bfloat16* __restrict__ W2t,
    const float* __restrict__ b2, const float* __restrict__ zin,
    float* __restrict__ zout, float* __restrict__ logdet)
{
  __shared__ __align__(16) char smem[47232];   // 16384 A + 30848 (B / ep union)
  const int tid = threadIdx.x;
  const int lane = tid & 63;
  const int w = tid >> 6;
  const int m0 = blockIdx.x * 128;
  const int n0 = blockIdx.y * 240;
  const int lrow = lane >> 3;
  const int scol = ((lane & 7) ^ lrow) << 4;
  const int fofs0 = ((lane >> 4) << 4) ^ ((lane & 7) << 4);
  const int arow = w * 32 + (lane & 15);
  const int brow = (lane & 15);

  f32x4 acc[2][15];
  #pragma unroll
  for (int i = 0; i < 2; ++i)
    #pragma unroll
    for (int j = 0; j < 15; ++j) acc[i][j] = (f32x4){0.f, 0.f, 0.f, 0.f};

  float b2v[15];
  #pragma unroll
  for (int fn = 0; fn < 15; ++fn) b2v[fn] = b2[n0 + fn * 16 + (lane & 15)];

  const char* Abase = (const char*)Hin + (size_t)(m0 + lrow) * 2048 + scol;
  const char* Bbase = (const char*)W2t + (size_t)(n0 + lrow) * 2048 + scol;

  for (int kt = 0; kt < 16; ++kt) {
    const int k0b = kt * 128;
    __syncthreads();
    for (int c = w; c < 46; c += 4) {          // 16 A chunks + 30 B chunks
      if (c < 16) gload_lds16(Abase + (size_t)c * 16384 + k0b, smem + c * 1024);
      else        gload_lds16(Bbase + (size_t)(c - 16) * 16384 + k0b,
                              smem + 16384 + (c - 16) * 1024);
    }
    asm volatile("s_waitcnt vmcnt(0)" ::: "memory");
    __syncthreads();
    #pragma unroll
    for (int ks = 0; ks < 2; ++ks) {
      const int fo = fofs0 ^ (ks << 6);
      bf16x8 a0 = *(const bf16x8*)(smem + arow * 128 + fo);
      bf16x8 a1 = *(const bf16x8*)(smem + (arow + 16) * 128 + fo);
      #pragma unroll
      for (int fn = 0; fn < 15; ++fn) {
        bf16x8 bb = *(const bf16x8*)(smem + 16384 + (brow + fn * 16) * 128 + fo);
        acc[0][fn] = __builtin_amdgcn_mfma_f32_16x16x32_bf16(a0, bb, acc[0][fn], 0, 0, 0);
        acc[1][fn] = __builtin_amdgcn_mfma_f32_16x16x32_bf16(a1, bb, acc[1][fn], 0, 0, 0);
      }
    }
  }

  // ---- fused NCP epilogue, 4 chunks of 32 rows ----
  const int r = tid >> 3;                      // 0..31
  const int g = tid & 7;                       // t-group within tile
  const int tglob = blockIdx.y * 8 + g;
  float* ep = (float*)(smem + 16384);          // [32][241] f32

  for (int ch = 0; ch < 4; ++ch) {
    __syncthreads();
    if (w == ch) {                             // wave ch owns rows ch*32..+31
      #pragma unroll
      for (int mf = 0; mf < 2; ++mf) {
        const int rbase = mf * 16 + ((lane >> 4) << 2);
        #pragma unroll
        for (int fn = 0; fn < 15; ++fn) {
          const int col = fn * 16 + (lane & 15);
          #pragma unroll
          for (int j = 0; j < 4; ++j)
            ep[(rbase + j) * 241 + col] = acc[mf][fn][j] + b2v[fn];
        }
      }
    }
    __syncthreads();

    const int bidx = m0 + ch * 32 + r;
    const float* o = ep + r * 241 + g * 30;    // 30 values: [e*3 + {a,b,q}]
    const float phi = zin[(size_t)bidx * 1024 + 2 * tglob + 1];
    const float x = tanf(0.5f * (phi - PI_F));
    const float x2p1 = fmaf(x, x, 1.0f);

    float q[10], mx = -1e30f;
    #pragma unroll
    for (int e = 0; e < 10; ++e) { q[e] = o[3 * e + 2]; mx = fmaxf(mx, q[e]); }

    float s = 0.f, outv = 0.f, dsum = 0.f;
    #pragma unroll
    for (int e = 0; e < 10; ++e) {
      float re = __expf(q[e] - mx);
      s += re;
      float av = o[3 * e];
      float aa = fmaxf(av, 0.f) + __logf(1.f + __expf(-fabsf(av))) + 0.001f;
      float u = fmaf(aa, x, o[3 * e + 1]);
      float hh = fmaf(2.f, atanf(u), PI_F);
      outv = fmaf(re, hh, outv);
      dsum = fmaf(re, aa * x2p1 / fmaf(u, u, 1.f), dsum);
    }
    float inv = 1.f / s;
    zout[(size_t)bidx * 1024 + 2 * tglob + 1] = outv * inv;

    float ld = __logf(dsum * inv);
    ld += __shfl_xor(ld, 1);
    ld += __shfl_xor(ld, 2);
    ld += __shfl_xor(ld, 4);
    if (g == 0) atomicAdd(&logdet[bidx], ld);
  }
}

// ---------------------------------------------------------------------------
extern "C" void kernel_launch(void* const* d_in, const int* in_sizes, int n_in,
                              void* d_out, int out_size, void* d_ws, size_t ws_size,
                              hipStream_t stream) {
  const float* z  = (const float*)d_in[0];
  const float* W1 = (const float*)d_in[1];
  const float* b1 = (const float*)d_in[2];
  const float* W2 = (const float*)d_in[3];
  const float* b2 = (const float*)d_in[4];

  float* zout   = (float*)d_out;               // 8192*1024
  float* logdet = zout + (size_t)8192 * 1024;  // 8192

  char* ws = (char*)d_ws;
  __hip_bfloat16* featB = (__hip_bfloat16*)ws;                     // 16 MB
  __hip_bfloat16* hB    = (__hip_bfloat16*)(ws + 16777216);        // 16 MB
  __hip_bfloat16* W1T   = (__hip_bfloat16*)(ws + 33554432);        //  2 MB
  __hip_bfloat16* W2T   = (__hip_bfloat16*)(ws + 35651584);        // 30 MB

  prep_feat_kernel<<<16384, 256, 0, stream>>>(z, featB, zout, logdet);
  transpose_bf16_kernel<<<dim3(32, 32), dim3(32, 8), 0, stream>>>(W1, W1T, 1024, 1024);
  transpose_bf16_kernel<<<dim3(480, 32), dim3(32, 8), 0, stream>>>(W2, W2T, 1024, 15360);
  gemm1_kernel<<<dim3(64, 8), 256, 0, stream>>>(featB, W1T, b1, hB);
  gemm2_ncp_kernel<<<dim3(64, 64), 256, 0, stream>>>(hB, W2T, b2, z, zout, logdet);
}